// Round 9
// baseline (34.199 us; speedup 1.0000x reference)
//
#include <hip/hip_runtime.h>

#define MARGIN 0.2f
#define EPSF   1e-16f

constexpr int BSZ = 512;   // batch
constexpr int DIM = 1024;  // embedding dim

typedef __attribute__((ext_vector_type(8))) short    bf16x8;
typedef __attribute__((ext_vector_type(4))) unsigned uint4v;
typedef __attribute__((ext_vector_type(4))) float    f32x4;

// 8x f32 -> 8x bf16 via v_cvt_pk_bf16_f32 (RNE). A and B use the same packing;
// dot products are k-permutation invariant, so in-lane order is free.
__device__ __forceinline__ bf16x8 cvt8(float4 a, float4 b) {
    uint4v u;
    asm("v_cvt_pk_bf16_f32 %0, %1, %2" : "=v"(u[0]) : "v"(a.x), "v"(a.y));
    asm("v_cvt_pk_bf16_f32 %0, %1, %2" : "=v"(u[1]) : "v"(a.z), "v"(a.w));
    asm("v_cvt_pk_bf16_f32 %0, %1, %2" : "=v"(u[2]) : "v"(b.x), "v"(b.y));
    asm("v_cvt_pk_bf16_f32 %0, %1, %2" : "=v"(u[3]) : "v"(b.z), "v"(b.w));
    return __builtin_bit_cast(bf16x8, u);
}

// ---------------- Node 1: MFMA GEMM (R8 structure, unchanged) ---------------
// 1024 blocks x 4 waves; one 16x16 tile/block; K split 4 ways across waves;
// LDS combine in fixed order. XCD-bijective tile swizzle. Block 0 zeroes ctr.
// mfma_f32_16x16x32_bf16: A/B row|col = lane&15, k = (lane>>4)*8 + j;
// C/D: col = lane&15, row = (lane>>4)*4 + q.
__global__ void __launch_bounds__(256) mfma_gemm(const float* __restrict__ I,
                                                 const float* __restrict__ S,
                                                 float* __restrict__ pw,
                                                 unsigned* __restrict__ ctr) {
    __shared__ f32x4 part[3][64];

    const int tid  = threadIdx.x;
    const int lane = tid & 63;
    const int w    = tid >> 6;                       // K quarter 0..3
    const int tile = ((blockIdx.x & 7) << 7) | (blockIdx.x >> 3);  // bijective
    const int tr   = (tile >> 5) * 16;               // anchor base
    const int tc   = (tile & 31) * 16;               // negative base
    const int r    = lane & 15;
    const int ko   = (lane >> 4) * 8;

    if (blockIdx.x == 0 && tid == 0) *ctr = 0u;      // for node 2's last-block

    const float* Ab = I + (size_t)(tr + r) * DIM + w * 256 + ko;
    const float* Bb = S + (size_t)(tc + r) * DIM + w * 256 + ko;

    f32x4 acc0 = {0.f, 0.f, 0.f, 0.f};
    f32x4 acc1 = {0.f, 0.f, 0.f, 0.f};
#pragma unroll
    for (int t = 0; t < 8; t += 2) {                 // 8 k-steps, 2 acc chains
        acc0 = __builtin_amdgcn_mfma_f32_16x16x32_bf16(
                   cvt8(*(const float4*)(Ab + t * 32),      *(const float4*)(Ab + t * 32 + 4)),
                   cvt8(*(const float4*)(Bb + t * 32),      *(const float4*)(Bb + t * 32 + 4)),
                   acc0, 0, 0, 0);
        acc1 = __builtin_amdgcn_mfma_f32_16x16x32_bf16(
                   cvt8(*(const float4*)(Ab + t * 32 + 32), *(const float4*)(Ab + t * 32 + 36)),
                   cvt8(*(const float4*)(Bb + t * 32 + 32), *(const float4*)(Bb + t * 32 + 36)),
                   acc1, 0, 0, 0);
    }
    acc0 += acc1;

    if (w) part[w - 1][lane] = acc0;
    __syncthreads();
    if (w == 0) {
        acc0 += part[0][lane];
        acc0 += part[1][lane];
        acc0 += part[2][lane];
        const int orow = tr + (lane >> 4) * 4;
        const int ocol = tc + r;
#pragma unroll
        for (int q = 0; q < 4; ++q)
            pw[(orow + q) * BSZ + ocol] = acc0[q];
    }
}

// ---------------- Node 2: triplet reduce + last-block finalize --------------
// 512 blocks x 256 thr, one block per anchor. Partials to arrays (fully
// written, no init, no float atomics); last block (ctr) re-reduces them with
// device-scope loads (XCD-coherence-safe) and writes out.
__global__ void __launch_bounds__(256) triplet_reduce(const float* __restrict__ pw,
                                                      const int*   __restrict__ labels,
                                                      float* __restrict__ psum,
                                                      float* __restrict__ pcnt,
                                                      unsigned* __restrict__ ctr,
                                                      float* __restrict__ out) {
    __shared__ float pwrow[BSZ];
    __shared__ int   lab[BSZ];
    __shared__ int   poslist[BSZ];
    __shared__ int   npos_sh;
    __shared__ float wsum[4];
    __shared__ int   wcnt[4];
    __shared__ unsigned is_last;

    const int a   = blockIdx.x;
    const int tid = threadIdx.x;

    if (tid == 0) npos_sh = 0;
    if (tid < 128) {                          // vectorized stage: 2 KB + 2 KB
        ((float4*)pwrow)[tid] = ((const float4*)(pw + (size_t)a * BSZ))[tid];
        ((int4*)lab)[tid]     = ((const int4*)labels)[tid];
    }
    __syncthreads();

    const int la = lab[a];
    for (int p = tid; p < BSZ; p += 256) {
        if (lab[p] == la) {
            int idx = atomicAdd(&npos_sh, 1);
            poslist[idx] = p;
        }
    }
    __syncthreads();
    const int npos = npos_sh;

    float sum = 0.f;
    int   cnt = 0;
    for (int n = tid; n < BSZ; n += 256) {
        if (lab[n] != la) {
            const float pn = pwrow[n];
            for (int i = 0; i < npos; ++i) {
                const float v = pwrow[poslist[i]] - pn + MARGIN;
                sum += fmaxf(v, 0.f);
                cnt += (v > EPSF) ? 1 : 0;
            }
        }
    }

#pragma unroll
    for (int off = 32; off > 0; off >>= 1) {
        sum += __shfl_down(sum, off);
        cnt += __shfl_down(cnt, off);
    }
    const int wid = tid >> 6, lane = tid & 63;
    if (lane == 0) { wsum[wid] = sum; wcnt[wid] = cnt; }
    __syncthreads();

    if (tid == 0) {
        psum[a] = wsum[0] + wsum[1] + wsum[2] + wsum[3];
        pcnt[a] = (float)(wcnt[0] + wcnt[1] + wcnt[2] + wcnt[3]);
        __threadfence();                       // partials visible device-wide
        const unsigned old = atomicAdd(ctr, 1u);
        is_last = (old == (unsigned)(BSZ - 1)) ? 1u : 0u;
    }
    __syncthreads();

    if (is_last) {                             // 512th block: final reduction
        float s = 0.f, c = 0.f;
        for (int i = tid; i < BSZ; i += 256) {
            s += __hip_atomic_load(&psum[i], __ATOMIC_RELAXED, __HIP_MEMORY_SCOPE_AGENT);
            c += __hip_atomic_load(&pcnt[i], __ATOMIC_RELAXED, __HIP_MEMORY_SCOPE_AGENT);
        }
#pragma unroll
        for (int off = 32; off > 0; off >>= 1) {
            s += __shfl_down(s, off);
            c += __shfl_down(c, off);
        }
        if (lane == 0) { wsum[wid] = s; wcnt[wid] = (int)c; }   // reuse LDS
        __syncthreads();
        if (tid == 0) {
            const float S_ = wsum[0] + wsum[1] + wsum[2] + wsum[3];
            const float C_ = (float)(wcnt[0] + wcnt[1] + wcnt[2] + wcnt[3]);
            out[0] = S_ / (C_ + EPSF);
        }
    }
}

extern "C" void kernel_launch(void* const* d_in, const int* in_sizes, int n_in,
                              void* d_out, int out_size, void* d_ws, size_t ws_size,
                              hipStream_t stream) {
    const int*   labels = (const int*)d_in[0];
    const float* img    = (const float*)d_in[1];
    const float* sen    = (const float*)d_in[2];
    float* out = (float*)d_out;

    // workspace: ctr (zeroed by gemm), pw, psum/pcnt (fully written per call)
    unsigned* ctr  = (unsigned*)d_ws;
    float*    pw   = (float*)((char*)d_ws + 256);                         // 1 MB
    float*    psum = (float*)((char*)d_ws + 256 + (1u << 20));            // 2 KB
    float*    pcnt = (float*)((char*)d_ws + 256 + (1u << 20) + 2048);     // 2 KB

    mfma_gemm<<<1024, 256, 0, stream>>>(img, sen, pw, ctr);
    triplet_reduce<<<BSZ, 256, 0, stream>>>(pw, labels, psum, pcnt, ctr, out);
}

// Round 10
// 30.520 us; speedup vs baseline: 1.1205x; 1.1205x over previous
//
#include <hip/hip_runtime.h>

#define MARGIN 0.2f
#define EPSF   1e-16f

constexpr int BSZ = 512;   // batch
constexpr int DIM = 1024;  // embedding dim

typedef __attribute__((ext_vector_type(8))) short    bf16x8;
typedef __attribute__((ext_vector_type(4))) unsigned uint4v;
typedef __attribute__((ext_vector_type(4))) float    f32x4;

// 8x f32 -> 8x bf16 via v_cvt_pk_bf16_f32 (RNE). A and B use the same packing;
// dot products are k-permutation invariant, so in-lane order is free.
__device__ __forceinline__ bf16x8 cvt8(float4 a, float4 b) {
    uint4v u;
    asm("v_cvt_pk_bf16_f32 %0, %1, %2" : "=v"(u[0]) : "v"(a.x), "v"(a.y));
    asm("v_cvt_pk_bf16_f32 %0, %1, %2" : "=v"(u[1]) : "v"(a.z), "v"(a.w));
    asm("v_cvt_pk_bf16_f32 %0, %1, %2" : "=v"(u[2]) : "v"(b.x), "v"(b.y));
    asm("v_cvt_pk_bf16_f32 %0, %1, %2" : "=v"(u[3]) : "v"(b.z), "v"(b.w));
    return __builtin_bit_cast(bf16x8, u);
}

// ---------------- Node 1: MFMA GEMM (R8 structure, unchanged) ---------------
// 1024 blocks x 4 waves; one 16x16 tile/block; K split 4 ways across waves;
// LDS combine in fixed order; XCD-bijective tile swizzle. Block 0 zeroes ctr
// (plain store; kernel-boundary fence makes it visible to node 2).
__global__ void __launch_bounds__(256) mfma_gemm(const float* __restrict__ I,
                                                 const float* __restrict__ S,
                                                 float* __restrict__ pw,
                                                 unsigned* __restrict__ ctr) {
    __shared__ f32x4 part[3][64];

    const int tid  = threadIdx.x;
    const int lane = tid & 63;
    const int w    = tid >> 6;                       // K quarter 0..3
    const int tile = ((blockIdx.x & 7) << 7) | (blockIdx.x >> 3);  // bijective
    const int tr   = (tile >> 5) * 16;               // anchor base
    const int tc   = (tile & 31) * 16;               // negative base
    const int r    = lane & 15;
    const int ko   = (lane >> 4) * 8;

    if (blockIdx.x == 0 && tid == 0) *ctr = 0u;

    const float* Ab = I + (size_t)(tr + r) * DIM + w * 256 + ko;
    const float* Bb = S + (size_t)(tc + r) * DIM + w * 256 + ko;

    f32x4 acc0 = {0.f, 0.f, 0.f, 0.f};
    f32x4 acc1 = {0.f, 0.f, 0.f, 0.f};
#pragma unroll
    for (int t = 0; t < 8; t += 2) {                 // 8 k-steps, 2 acc chains
        acc0 = __builtin_amdgcn_mfma_f32_16x16x32_bf16(
                   cvt8(*(const float4*)(Ab + t * 32),      *(const float4*)(Ab + t * 32 + 4)),
                   cvt8(*(const float4*)(Bb + t * 32),      *(const float4*)(Bb + t * 32 + 4)),
                   acc0, 0, 0, 0);
        acc1 = __builtin_amdgcn_mfma_f32_16x16x32_bf16(
                   cvt8(*(const float4*)(Ab + t * 32 + 32), *(const float4*)(Ab + t * 32 + 36)),
                   cvt8(*(const float4*)(Bb + t * 32 + 32), *(const float4*)(Bb + t * 32 + 36)),
                   acc1, 0, 0, 0);
    }
    acc0 += acc1;

    if (w) part[w - 1][lane] = acc0;
    __syncthreads();
    if (w == 0) {
        acc0 += part[0][lane];
        acc0 += part[1][lane];
        acc0 += part[2][lane];
        const int orow = tr + (lane >> 4) * 4;
        const int ocol = tc + r;
#pragma unroll
        for (int q = 0; q < 4; ++q)
            pw[(orow + q) * BSZ + ocol] = acc0[q];
    }
}

// ---------------- Node 2: triplet reduce + fence-free last-block finalize ---
// 512 blocks x 256 thr, one block per anchor. Partial (sum,cnt) packed into
// ONE 64-bit agent-scope atomic store (write-through -> no L2 writeback
// needed); hand-rolled release: s_waitcnt vmcnt(0) then relaxed agent RMW on
// ctr. Last block (old==511) atomic-loads the 512 packed partials (performed
// at the coherent point) and finalizes. Fully deterministic.
__global__ void __launch_bounds__(256) triplet_reduce(const float* __restrict__ pw,
                                                      const int*   __restrict__ labels,
                                                      unsigned long long* __restrict__ part,
                                                      unsigned* __restrict__ ctr,
                                                      float* __restrict__ out) {
    __shared__ float pwrow[BSZ];
    __shared__ int   lab[BSZ];
    __shared__ int   poslist[BSZ];
    __shared__ int   npos_sh;
    __shared__ float wsum[4];
    __shared__ int   wcnt[4];
    __shared__ unsigned is_last;

    const int a   = blockIdx.x;
    const int tid = threadIdx.x;

    if (tid == 0) npos_sh = 0;
    if (tid < 128) {                          // vectorized stage: 2 KB + 2 KB
        ((float4*)pwrow)[tid] = ((const float4*)(pw + (size_t)a * BSZ))[tid];
        ((int4*)lab)[tid]     = ((const int4*)labels)[tid];
    }
    __syncthreads();

    const int la = lab[a];
    for (int p = tid; p < BSZ; p += 256) {
        if (lab[p] == la) {
            int idx = atomicAdd(&npos_sh, 1);
            poslist[idx] = p;
        }
    }
    __syncthreads();
    const int npos = npos_sh;

    float sum = 0.f;
    int   cnt = 0;
    for (int n = tid; n < BSZ; n += 256) {
        if (lab[n] != la) {
            const float pn = pwrow[n];
            for (int i = 0; i < npos; ++i) {
                const float v = pwrow[poslist[i]] - pn + MARGIN;
                sum += fmaxf(v, 0.f);
                cnt += (v > EPSF) ? 1 : 0;
            }
        }
    }

#pragma unroll
    for (int off = 32; off > 0; off >>= 1) {
        sum += __shfl_down(sum, off);
        cnt += __shfl_down(cnt, off);
    }
    const int wid = tid >> 6, lane = tid & 63;
    if (lane == 0) { wsum[wid] = sum; wcnt[wid] = cnt; }
    __syncthreads();

    if (tid == 0) {
        const float s = wsum[0] + wsum[1] + wsum[2] + wsum[3];
        const float c = (float)(wcnt[0] + wcnt[1] + wcnt[2] + wcnt[3]);
        float2 pk2 = make_float2(s, c);
        // agent-scope atomic store: write-through to coherent point, no wbl2
        __hip_atomic_store(&part[a], __builtin_bit_cast(unsigned long long, pk2),
                           __ATOMIC_RELAXED, __HIP_MEMORY_SCOPE_AGENT);
        // hand-rolled release: wait for the store's ack, then relaxed RMW
        asm volatile("s_waitcnt vmcnt(0)" ::: "memory");
        const unsigned old = __hip_atomic_fetch_add(ctr, 1u, __ATOMIC_RELAXED,
                                                    __HIP_MEMORY_SCOPE_AGENT);
        is_last = (old == (unsigned)(BSZ - 1)) ? 1u : 0u;
    }
    __syncthreads();

    if (is_last) {                             // 512th block: finalize
        float s = 0.f, c = 0.f;
#pragma unroll
        for (int j = 0; j < 2; ++j) {
            const unsigned long long v =
                __hip_atomic_load(&part[tid + j * 256], __ATOMIC_RELAXED,
                                  __HIP_MEMORY_SCOPE_AGENT);
            const float2 f = __builtin_bit_cast(float2, v);
            s += f.x;
            c += f.y;
        }
#pragma unroll
        for (int off = 32; off > 0; off >>= 1) {
            s += __shfl_down(s, off);
            c += __shfl_down(c, off);
        }
        if (lane == 0) { wsum[wid] = s; wcnt[wid] = (int)c; }   // reuse LDS
        __syncthreads();
        if (tid == 0) {
            const float S_ = wsum[0] + wsum[1] + wsum[2] + wsum[3];
            const float C_ = (float)(wcnt[0] + wcnt[1] + wcnt[2] + wcnt[3]);
            out[0] = S_ / (C_ + EPSF);
        }
    }
}

extern "C" void kernel_launch(void* const* d_in, const int* in_sizes, int n_in,
                              void* d_out, int out_size, void* d_ws, size_t ws_size,
                              hipStream_t stream) {
    const int*   labels = (const int*)d_in[0];
    const float* img    = (const float*)d_in[1];
    const float* sen    = (const float*)d_in[2];
    float* out = (float*)d_out;

    // workspace: ctr (zeroed by node 1), pw (1 MB), packed partials (4 KB)
    unsigned*           ctr  = (unsigned*)d_ws;
    float*              pw   = (float*)((char*)d_ws + 256);
    unsigned long long* part = (unsigned long long*)((char*)d_ws + 256 + (1u << 20));

    mfma_gemm<<<1024, 256, 0, stream>>>(img, sen, pw, ctr);
    triplet_reduce<<<BSZ, 256, 0, stream>>>(pw, labels, part, ctr, out);
}

// Round 11
// 26.131 us; speedup vs baseline: 1.3088x; 1.1680x over previous
//
#include <hip/hip_runtime.h>

#define MARGIN 0.2f
#define EPSF   1e-16f

constexpr int BSZ  = 512;   // batch
constexpr int DIM  = 1024;  // embedding dim
constexpr int RBLK = 128;   // reduce blocks (4 anchors each)

typedef __attribute__((ext_vector_type(8))) short    bf16x8;
typedef __attribute__((ext_vector_type(4))) unsigned uint4v;
typedef __attribute__((ext_vector_type(4))) float    f32x4;

// 8x f32 -> 8x bf16 via v_cvt_pk_bf16_f32 (RNE). A and B use the same packing;
// dot products are k-permutation invariant, so in-lane order is free.
__device__ __forceinline__ bf16x8 cvt8(float4 a, float4 b) {
    uint4v u;
    asm("v_cvt_pk_bf16_f32 %0, %1, %2" : "=v"(u[0]) : "v"(a.x), "v"(a.y));
    asm("v_cvt_pk_bf16_f32 %0, %1, %2" : "=v"(u[1]) : "v"(a.z), "v"(a.w));
    asm("v_cvt_pk_bf16_f32 %0, %1, %2" : "=v"(u[2]) : "v"(b.x), "v"(b.y));
    asm("v_cvt_pk_bf16_f32 %0, %1, %2" : "=v"(u[3]) : "v"(b.z), "v"(b.w));
    return __builtin_bit_cast(bf16x8, u);
}

// ---------------- Node 1: MFMA GEMM (R8 structure, unchanged) ---------------
// 1024 blocks x 4 waves; one 16x16 tile/block; K split 4 ways across waves;
// LDS combine in fixed order; XCD-bijective tile swizzle. Block 0 zeroes ctr.
__global__ void __launch_bounds__(256) mfma_gemm(const float* __restrict__ I,
                                                 const float* __restrict__ S,
                                                 float* __restrict__ pw,
                                                 unsigned* __restrict__ ctr) {
    __shared__ f32x4 part[3][64];

    const int tid  = threadIdx.x;
    const int lane = tid & 63;
    const int w    = tid >> 6;                       // K quarter 0..3
    const int tile = ((blockIdx.x & 7) << 7) | (blockIdx.x >> 3);  // bijective
    const int tr   = (tile >> 5) * 16;               // anchor base
    const int tc   = (tile & 31) * 16;               // negative base
    const int r    = lane & 15;
    const int ko   = (lane >> 4) * 8;

    if (blockIdx.x == 0 && tid == 0) *ctr = 0u;

    const float* Ab = I + (size_t)(tr + r) * DIM + w * 256 + ko;
    const float* Bb = S + (size_t)(tc + r) * DIM + w * 256 + ko;

    f32x4 acc0 = {0.f, 0.f, 0.f, 0.f};
    f32x4 acc1 = {0.f, 0.f, 0.f, 0.f};
#pragma unroll
    for (int t = 0; t < 8; t += 2) {                 // 8 k-steps, 2 acc chains
        acc0 = __builtin_amdgcn_mfma_f32_16x16x32_bf16(
                   cvt8(*(const float4*)(Ab + t * 32),      *(const float4*)(Ab + t * 32 + 4)),
                   cvt8(*(const float4*)(Bb + t * 32),      *(const float4*)(Bb + t * 32 + 4)),
                   acc0, 0, 0, 0);
        acc1 = __builtin_amdgcn_mfma_f32_16x16x32_bf16(
                   cvt8(*(const float4*)(Ab + t * 32 + 32), *(const float4*)(Ab + t * 32 + 36)),
                   cvt8(*(const float4*)(Bb + t * 32 + 32), *(const float4*)(Bb + t * 32 + 36)),
                   acc1, 0, 0, 0);
    }
    acc0 += acc1;

    if (w) part[w - 1][lane] = acc0;
    __syncthreads();
    if (w == 0) {
        acc0 += part[0][lane];
        acc0 += part[1][lane];
        acc0 += part[2][lane];
        const int orow = tr + (lane >> 4) * 4;
        const int ocol = tc + r;
#pragma unroll
        for (int q = 0; q < 4; ++q)
            pw[(orow + q) * BSZ + ocol] = acc0[q];
    }
}

// ---------------- Node 2: 4-anchor triplet reduce + de-contended finalize ---
// 128 blocks x 256 thr; wave w owns anchor 4*blk+w end-to-end. Ballot-walked
// positives (ascending p, deterministic), register-cached negatives. One
// packed agent-scope atomic store per block + vmcnt-acked relaxed ctr RMW;
// last block (old==127) loads 128 partials and finalizes.
__global__ void __launch_bounds__(256) triplet_reduce(const float* __restrict__ pw,
                                                      const int*   __restrict__ labels,
                                                      unsigned long long* __restrict__ part,
                                                      unsigned* __restrict__ ctr,
                                                      float* __restrict__ out) {
    __shared__ int   lab[BSZ];
    __shared__ float rows[4][BSZ];
    __shared__ float wsum_s[4];
    __shared__ int   wcnt_s[4];
    __shared__ unsigned is_last;

    const int tid  = threadIdx.x;
    const int lane = tid & 63;
    const int w    = tid >> 6;
    const int a0   = blockIdx.x * 4;

    if (tid < 128) ((int4*)lab)[tid] = ((const int4*)labels)[tid];
    // 4 contiguous pw rows = 8 KB = 512 float4, two coalesced rounds
    ((float4*)rows)[tid]       = ((const float4*)(pw + (size_t)a0 * BSZ))[tid];
    ((float4*)rows)[tid + 256] = ((const float4*)(pw + (size_t)a0 * BSZ))[tid + 256];
    __syncthreads();

    const int la = lab[a0 + w];

    // cache this lane's 8 negatives + mask
    float vn[8];
    bool  ng[8];
#pragma unroll
    for (int j = 0; j < 8; ++j) {
        const int n = j * 64 + lane;
        vn[j] = rows[w][n];
        ng[j] = (lab[n] != la);
    }

    float sum = 0.f;
    int   cnt = 0;
    for (int p0 = 0; p0 < BSZ; p0 += 64) {
        unsigned long long m = __ballot(lab[p0 + lane] == la);
        while (m) {                                   // ascending p, uniform
            const int p = p0 + __ffsll((long long)m) - 1;
            m &= m - 1;
            const float pv = rows[w][p] + MARGIN;     // LDS broadcast
#pragma unroll
            for (int j = 0; j < 8; ++j) {
                const float v = pv - vn[j];
                sum += ng[j] ? fmaxf(v, 0.f) : 0.f;
                cnt += (ng[j] && v > EPSF) ? 1 : 0;
            }
        }
    }

#pragma unroll
    for (int off = 32; off > 0; off >>= 1) {
        sum += __shfl_down(sum, off);
        cnt += __shfl_down(cnt, off);
    }
    if (lane == 0) { wsum_s[w] = sum; wcnt_s[w] = cnt; }
    __syncthreads();

    if (tid == 0) {
        const float s = wsum_s[0] + wsum_s[1] + wsum_s[2] + wsum_s[3];
        const float c = (float)(wcnt_s[0] + wcnt_s[1] + wcnt_s[2] + wcnt_s[3]);
        const float2 pk2 = make_float2(s, c);
        __hip_atomic_store(&part[blockIdx.x],
                           __builtin_bit_cast(unsigned long long, pk2),
                           __ATOMIC_RELAXED, __HIP_MEMORY_SCOPE_AGENT);
        asm volatile("s_waitcnt vmcnt(0)" ::: "memory");   // store performed
        const unsigned old = __hip_atomic_fetch_add(ctr, 1u, __ATOMIC_RELAXED,
                                                    __HIP_MEMORY_SCOPE_AGENT);
        is_last = (old == (unsigned)(RBLK - 1)) ? 1u : 0u;
    }
    __syncthreads();

    if (is_last) {                                    // 128th block: finalize
        float s = 0.f, c = 0.f;
        if (tid < RBLK) {
            const unsigned long long v =
                __hip_atomic_load(&part[tid], __ATOMIC_RELAXED,
                                  __HIP_MEMORY_SCOPE_AGENT);
            const float2 f = __builtin_bit_cast(float2, v);
            s = f.x;
            c = f.y;
        }
#pragma unroll
        for (int off = 32; off > 0; off >>= 1) {
            s += __shfl_down(s, off);
            c += __shfl_down(c, off);
        }
        if (lane == 0) { wsum_s[w] = s; wcnt_s[w] = (int)c; }
        __syncthreads();
        if (tid == 0) {
            const float S_ = wsum_s[0] + wsum_s[1] + wsum_s[2] + wsum_s[3];
            const float C_ = (float)(wcnt_s[0] + wcnt_s[1] + wcnt_s[2] + wcnt_s[3]);
            out[0] = S_ / (C_ + EPSF);
        }
    }
}

extern "C" void kernel_launch(void* const* d_in, const int* in_sizes, int n_in,
                              void* d_out, int out_size, void* d_ws, size_t ws_size,
                              hipStream_t stream) {
    const int*   labels = (const int*)d_in[0];
    const float* img    = (const float*)d_in[1];
    const float* sen    = (const float*)d_in[2];
    float* out = (float*)d_out;

    // workspace: ctr (zeroed by node 1), pw (1 MB), packed partials (1 KB)
    unsigned*           ctr  = (unsigned*)d_ws;
    float*              pw   = (float*)((char*)d_ws + 256);
    unsigned long long* part = (unsigned long long*)((char*)d_ws + 256 + (1u << 20));

    mfma_gemm<<<1024, 256, 0, stream>>>(img, sen, pw, ctr);
    triplet_reduce<<<RBLK, 256, 0, stream>>>(pw, labels, part, ctr, out);
}